// Round 1
// baseline (897.630 us; speedup 1.0000x reference)
//
#include <hip/hip_runtime.h>
#include <hip/hip_bf16.h>
#include <cstdint>
#include <cstddef>

// D = 64 hardcoded throughout (in_feats == hidden == 64).

static __device__ __forceinline__ uint32_t f32_to_bf16_bits(float f) {
    uint32_t u = __builtin_bit_cast(uint32_t, f);
    u += 0x7fffu + ((u >> 16) & 1u);   // round-to-nearest-even (no NaNs in this problem)
    return u >> 16;
}

static __device__ __forceinline__ void add_bf16x8(float* acc, uint4 q) {
    uint32_t w0 = q.x, w1 = q.y, w2 = q.z, w3 = q.w;
    acc[0] += __builtin_bit_cast(float, w0 << 16);
    acc[1] += __builtin_bit_cast(float, w0 & 0xffff0000u);
    acc[2] += __builtin_bit_cast(float, w1 << 16);
    acc[3] += __builtin_bit_cast(float, w1 & 0xffff0000u);
    acc[4] += __builtin_bit_cast(float, w2 << 16);
    acc[5] += __builtin_bit_cast(float, w2 & 0xffff0000u);
    acc[6] += __builtin_bit_cast(float, w3 << 16);
    acc[7] += __builtin_bit_cast(float, w3 & 0xffff0000u);
}

// ---------------------------------------------------------------- degree count
__global__ void deg_kernel(const int* __restrict__ ei, int* __restrict__ deg, int E) {
    int e = blockIdx.x * blockDim.x + threadIdx.x;
    if (e < E) {
        int dst = ei[E + e];
        atomicAdd(&deg[dst], 1);
    }
}

// -------------------------------------------------- exclusive scan + deg_inv_sqrt
// Single workgroup of 1024 threads; N=100K -> ~98 elements/thread.
__global__ __launch_bounds__(1024) void scan_kernel(const int* __restrict__ deg,
                                                    int* __restrict__ rowptr,
                                                    float* __restrict__ dis, int n) {
    __shared__ int sums[1024];
    int t = threadIdx.x;
    int per = (n + 1023) >> 10;
    int lo = t * per;
    int hi = min(n, lo + per);
    int s = 0;
    for (int i = lo; i < hi; ++i) s += deg[i];
    sums[t] = s;
    __syncthreads();
    // Hillis-Steele inclusive scan over 1024 partials
    for (int off = 1; off < 1024; off <<= 1) {
        int v = (t >= off) ? sums[t - off] : 0;
        __syncthreads();
        sums[t] += v;
        __syncthreads();
    }
    int run = sums[t] - s;  // exclusive base for this segment
    for (int i = lo; i < hi; ++i) {
        rowptr[i] = run;
        int d = deg[i];
        run += d;
        dis[i] = rsqrtf((float)(d + 1));  // +1 self-loop; always > 0
    }
    if (t == 1023) rowptr[n] = run;  // == E
}

// ---------------------------------------------------------------- CSR fill
__global__ void fill_kernel(const int* __restrict__ ei, const int* __restrict__ rowptr,
                            int* __restrict__ cursor, int* __restrict__ col, int E) {
    int e = blockIdx.x * blockDim.x + threadIdx.x;
    if (e < E) {
        int src = ei[e];
        int dst = ei[E + e];
        int p = atomicAdd(&cursor[dst], 1);
        col[rowptr[dst] + p] = src;
    }
}

// ---------------------------------------------------------------- GEMM [N,64]@[64,64]
// MODE 0: out = bf16( (x@W) * dis[row] )   (packed 2x bf16 per uint, 8 uint4/row)
// MODE 1: out = fp32( (x@W) + bias )
template <int MODE>
__global__ __launch_bounds__(256) void gemm_kernel(const float* __restrict__ x,
                                                   const float* __restrict__ W,
                                                   const float* __restrict__ dis,
                                                   const float* __restrict__ bias,
                                                   void* __restrict__ out, int n) {
    __shared__ float Wl[64 * 64];  // 16 KB, W[k*64 + j]
    int t = threadIdx.x;
    {
        const float4* W4 = (const float4*)W;
        float4* Wl4 = (float4*)Wl;
#pragma unroll
        for (int i = 0; i < 4; ++i) Wl4[t + i * 256] = W4[t + i * 256];
    }
    __syncthreads();

    int row = blockIdx.x * 256 + t;
    if (row >= n) return;

    const float4* xr = (const float4*)(x + (size_t)row * 64);
    float4 acc4[16];
#pragma unroll
    for (int p = 0; p < 16; ++p) acc4[p] = make_float4(0.f, 0.f, 0.f, 0.f);

    float4 xq = xr[0];
    for (int k4 = 0; k4 < 16; ++k4) {       // not unrolled: keeps code size sane
        float4 xn = xq;
        if (k4 < 15) xn = xr[k4 + 1];       // software prefetch of next x chunk
        float xs[4] = {xq.x, xq.y, xq.z, xq.w};
#pragma unroll
        for (int kk = 0; kk < 4; ++kk) {
            float xk = xs[kk];
            const float4* wr = (const float4*)&Wl[((k4 << 2) + kk) << 6];
#pragma unroll
            for (int j4 = 0; j4 < 16; ++j4) {
                float4 wv = wr[j4];   // wave-uniform address -> LDS broadcast
                acc4[j4].x = fmaf(xk, wv.x, acc4[j4].x);
                acc4[j4].y = fmaf(xk, wv.y, acc4[j4].y);
                acc4[j4].z = fmaf(xk, wv.z, acc4[j4].z);
                acc4[j4].w = fmaf(xk, wv.w, acc4[j4].w);
            }
        }
        xq = xn;
    }

    if (MODE == 0) {
        float s = dis[row];
        uint4* go = (uint4*)out;
#pragma unroll
        for (int p = 0; p < 8; ++p) {
            float4 a = acc4[2 * p];
            float4 b = acc4[2 * p + 1];
            uint4 o;
            o.x = (f32_to_bf16_bits(a.y * s) << 16) | f32_to_bf16_bits(a.x * s);
            o.y = (f32_to_bf16_bits(a.w * s) << 16) | f32_to_bf16_bits(a.z * s);
            o.z = (f32_to_bf16_bits(b.y * s) << 16) | f32_to_bf16_bits(b.x * s);
            o.w = (f32_to_bf16_bits(b.w * s) << 16) | f32_to_bf16_bits(b.z * s);
            go[(size_t)row * 8 + p] = o;
        }
    } else {
        const float4* b4 = (const float4*)bias;
        float4* fo = (float4*)out;
#pragma unroll
        for (int p = 0; p < 16; ++p) {
            float4 bb = b4[p];
            float4 a = acc4[p];
            a.x += bb.x; a.y += bb.y; a.z += bb.z; a.w += bb.w;
            fo[(size_t)row * 16 + p] = a;
        }
    }
}

// ---------------------------------------------------------------- pull aggregation
// One wave per dst node. 8 groups x 8 lanes: group g handles edges beg+g, beg+g+8, ...
// lane chunk (lane&7) covers features chk*8..chk*8+7 via one dwordx4 bf16 load.
// out[i] = relu( dis[i] * (g[i] + sum_{e in in(i)} g[col[e]]) + bias )
__global__ __launch_bounds__(256) void agg_kernel(const uint4* __restrict__ g,
                                                  const int* __restrict__ rowptr,
                                                  const int* __restrict__ col,
                                                  const float* __restrict__ dis,
                                                  const float* __restrict__ bias,
                                                  float* __restrict__ out, int n) {
    int wid = (blockIdx.x * 256 + threadIdx.x) >> 6;
    if (wid >= n) return;
    int lane = threadIdx.x & 63;
    int grp = lane >> 3;
    int chk = lane & 7;

    float acc[8];
#pragma unroll
    for (int j = 0; j < 8; ++j) acc[j] = 0.f;

    if (grp == 0) {  // self-loop term
        uint4 q = g[(size_t)wid * 8 + chk];
        add_bf16x8(acc, q);
    }

    int beg = rowptr[wid];
    int end = rowptr[wid + 1];
    for (int e = beg + grp; e < end; e += 8) {
        int s = col[e];                       // same addr across the 8-lane group
        uint4 q = g[(size_t)s * 8 + chk];     // 128B contiguous per group
        add_bf16x8(acc, q);
    }

    // reduce across the 8 groups (lanes with equal chk, stride 8)
#pragma unroll
    for (int m = 8; m < 64; m <<= 1) {
#pragma unroll
        for (int j = 0; j < 8; ++j) acc[j] += __shfl_xor(acc[j], m, 64);
    }

    if (grp == 0) {
        float dv = dis[wid];
        float4 o0, o1;
        const float* bb = bias + chk * 8;
        o0.x = fmaxf(fmaf(acc[0], dv, bb[0]), 0.f);
        o0.y = fmaxf(fmaf(acc[1], dv, bb[1]), 0.f);
        o0.z = fmaxf(fmaf(acc[2], dv, bb[2]), 0.f);
        o0.w = fmaxf(fmaf(acc[3], dv, bb[3]), 0.f);
        o1.x = fmaxf(fmaf(acc[4], dv, bb[4]), 0.f);
        o1.y = fmaxf(fmaf(acc[5], dv, bb[5]), 0.f);
        o1.z = fmaxf(fmaf(acc[6], dv, bb[6]), 0.f);
        o1.w = fmaxf(fmaf(acc[7], dv, bb[7]), 0.f);
        float4* fo = (float4*)out;
        fo[(size_t)wid * 16 + chk * 2 + 0] = o0;
        fo[(size_t)wid * 16 + chk * 2 + 1] = o1;
    }
}

// ---------------------------------------------------------------- launch
extern "C" void kernel_launch(void* const* d_in, const int* in_sizes, int n_in,
                              void* d_out, int out_size, void* d_ws, size_t ws_size,
                              hipStream_t stream) {
    const float* x  = (const float*)d_in[0];
    const int*   ei = (const int*)d_in[1];   // [2,E] int32 (harness converts integer dtypes)
    const float* W1 = (const float*)d_in[2];
    const float* b1 = (const float*)d_in[3];
    const float* W2 = (const float*)d_in[4];
    const float* b2 = (const float*)d_in[5];
    // Wq/bq/Wk/bk (d_in[6..9]) are dead: softmax over a length-1 axis is identity.
    const float* Wv = (const float*)d_in[10];
    const float* bv = (const float*)d_in[11];

    const int N = in_sizes[0] / 64;
    const int E = in_sizes[1] / 2;

    auto align_up = [](size_t v) { return (v + 255) & ~(size_t)255; };
    char* p = (char*)d_ws;
    int*   deg    = (int*)p;    p += align_up((size_t)N * 4);
    int*   cursor = (int*)p;    p += align_up((size_t)N * 4);
    int*   rowptr = (int*)p;    p += align_up((size_t)(N + 1) * 4);
    float* dis    = (float*)p;  p += align_up((size_t)N * 4);
    int*   col    = (int*)p;    p += align_up((size_t)E * 4);
    uint4* gbuf   = (uint4*)p;  p += align_up((size_t)N * 128);  // bf16 rows
    float* xbuf   = (float*)p;  p += align_up((size_t)N * 256);  // fp32 hidden

    hipMemsetAsync(deg, 0, (size_t)N * 4, stream);
    hipMemsetAsync(cursor, 0, (size_t)N * 4, stream);

    int ebl = (E + 255) / 256;
    int nbl = (N + 255) / 256;
    int abl = (N + 3) / 4;  // one wave per node, 4 waves per block

    deg_kernel<<<ebl, 256, 0, stream>>>(ei, deg, E);
    scan_kernel<<<1, 1024, 0, stream>>>(deg, rowptr, dis, N);
    fill_kernel<<<ebl, 256, 0, stream>>>(ei, rowptr, cursor, col, E);

    // layer 1: g = bf16(dis * (x@W1)); xbuf = relu(dis*Agg(g) + b1)
    gemm_kernel<0><<<nbl, 256, 0, stream>>>(x, W1, dis, nullptr, gbuf, N);
    agg_kernel<<<abl, 256, 0, stream>>>(gbuf, rowptr, col, dis, b1, xbuf, N);

    // layer 2
    gemm_kernel<0><<<nbl, 256, 0, stream>>>(xbuf, W2, dis, nullptr, gbuf, N);
    agg_kernel<<<abl, 256, 0, stream>>>(gbuf, rowptr, col, dis, b2, xbuf, N);

    // output: v = xbuf@Wv + bv (attention is identity at seq_len 1)
    gemm_kernel<1><<<nbl, 256, 0, stream>>>(xbuf, Wv, nullptr, bv, d_out, N);
}

// Round 2
// 658.836 us; speedup vs baseline: 1.3624x; 1.3624x over previous
//
#include <hip/hip_runtime.h>
#include <hip/hip_bf16.h>
#include <cstdint>
#include <cstddef>

// D = 64 hardcoded throughout (in_feats == hidden == 64).

static __device__ __forceinline__ uint32_t f32_to_bf16_bits(float f) {
    uint32_t u = __builtin_bit_cast(uint32_t, f);
    u += 0x7fffu + ((u >> 16) & 1u);   // round-to-nearest-even (no NaNs in this problem)
    return u >> 16;
}

static __device__ __forceinline__ void add_bf16x8(float* acc, uint4 q) {
    uint32_t w0 = q.x, w1 = q.y, w2 = q.z, w3 = q.w;
    acc[0] += __builtin_bit_cast(float, w0 << 16);
    acc[1] += __builtin_bit_cast(float, w0 & 0xffff0000u);
    acc[2] += __builtin_bit_cast(float, w1 << 16);
    acc[3] += __builtin_bit_cast(float, w1 & 0xffff0000u);
    acc[4] += __builtin_bit_cast(float, w2 << 16);
    acc[5] += __builtin_bit_cast(float, w2 & 0xffff0000u);
    acc[6] += __builtin_bit_cast(float, w3 << 16);
    acc[7] += __builtin_bit_cast(float, w3 & 0xffff0000u);
}

// ---------------------------------------------------------------- degree count
// 4 edges per thread via int4 on the dst half of edge_index.
__global__ void deg_kernel(const int* __restrict__ ei, int* __restrict__ deg, int E) {
    int t = blockIdx.x * blockDim.x + threadIdx.x;
    int E4 = E >> 2;
    if (t < E4) {
        int4 d = ((const int4*)(ei + E))[t];
        atomicAdd(&deg[d.x], 1);
        atomicAdd(&deg[d.y], 1);
        atomicAdd(&deg[d.z], 1);
        atomicAdd(&deg[d.w], 1);
    }
    // tail (E % 4 edges) handled by the first few threads
    if (t < (E & 3)) {
        atomicAdd(&deg[ei[E + (E4 << 2) + t]], 1);
    }
}

// ---------------------------------------------------------------- hierarchical scan
// S1: per-256-block sums
__global__ __launch_bounds__(256) void scan1_kernel(const int* __restrict__ deg,
                                                    int* __restrict__ bsum, int n) {
    int i = blockIdx.x * 256 + threadIdx.x;
    int v = (i < n) ? deg[i] : 0;
#pragma unroll
    for (int m = 1; m < 64; m <<= 1) v += __shfl_xor(v, m, 64);
    __shared__ int ws[4];
    if ((threadIdx.x & 63) == 0) ws[threadIdx.x >> 6] = v;
    __syncthreads();
    if (threadIdx.x == 0) bsum[blockIdx.x] = ws[0] + ws[1] + ws[2] + ws[3];
}

// S2: exclusive scan of block sums (nb <= 1024), single block
__global__ __launch_bounds__(1024) void scan2_kernel(int* __restrict__ bsum, int nb) {
    __shared__ int s[1024];
    int t = threadIdx.x;
    int v = (t < nb) ? bsum[t] : 0;
    s[t] = v;
    __syncthreads();
    for (int off = 1; off < 1024; off <<= 1) {
        int u = (t >= off) ? s[t - off] : 0;
        __syncthreads();
        s[t] += u;
        __syncthreads();
    }
    if (t < nb) bsum[t] = s[t] - v;  // exclusive
}

// S3: per-block rescan + rowptr/dis emit
__global__ __launch_bounds__(256) void scan3_kernel(const int* __restrict__ deg,
                                                    const int* __restrict__ bsum,
                                                    int* __restrict__ rowptr,
                                                    float* __restrict__ dis, int n) {
    __shared__ int s[256];
    int t = threadIdx.x;
    int i = blockIdx.x * 256 + t;
    int d = (i < n) ? deg[i] : 0;
    s[t] = d;
    __syncthreads();
    for (int off = 1; off < 256; off <<= 1) {
        int u = (t >= off) ? s[t - off] : 0;
        __syncthreads();
        s[t] += u;
        __syncthreads();
    }
    int ex = s[t] - d + bsum[blockIdx.x];
    if (i < n) {
        rowptr[i] = ex;
        dis[i] = rsqrtf((float)(d + 1));  // +1 self-loop; always > 0
    }
    if (i == n - 1) rowptr[n] = ex + d;  // == E
}

// ---------------------------------------------------------------- CSR fill
__global__ void fill_kernel(const int* __restrict__ ei, const int* __restrict__ rowptr,
                            int* __restrict__ cursor, int* __restrict__ col, int E) {
    int e = blockIdx.x * blockDim.x + threadIdx.x;
    if (e < E) {
        int src = ei[e];
        int dst = ei[E + e];
        int p = atomicAdd(&cursor[dst], 1);
        col[rowptr[dst] + p] = src;
    }
}

// ---------------------------------------------------------------- GEMM [N,64]@[64,64]
// MODE 0: out = bf16( (x@W) * dis[row] )   (packed 2x bf16 per uint, 8 uint4/row)
// MODE 1: out = fp32( (x@W) + bias )
template <int MODE>
__global__ __launch_bounds__(256) void gemm_kernel(const float* __restrict__ x,
                                                   const float* __restrict__ W,
                                                   const float* __restrict__ dis,
                                                   const float* __restrict__ bias,
                                                   void* __restrict__ out, int n) {
    __shared__ float Wl[64 * 64];  // 16 KB, W[k*64 + j]
    int t = threadIdx.x;
    {
        const float4* W4 = (const float4*)W;
        float4* Wl4 = (float4*)Wl;
#pragma unroll
        for (int i = 0; i < 4; ++i) Wl4[t + i * 256] = W4[t + i * 256];
    }
    __syncthreads();

    int row = blockIdx.x * 256 + t;
    if (row >= n) return;

    const float4* xr = (const float4*)(x + (size_t)row * 64);
    float4 acc4[16];
#pragma unroll
    for (int p = 0; p < 16; ++p) acc4[p] = make_float4(0.f, 0.f, 0.f, 0.f);

    float4 xq = xr[0];
    for (int k4 = 0; k4 < 16; ++k4) {
        float4 xn = xq;
        if (k4 < 15) xn = xr[k4 + 1];       // software prefetch of next x chunk
        float xs[4] = {xq.x, xq.y, xq.z, xq.w};
#pragma unroll
        for (int kk = 0; kk < 4; ++kk) {
            float xk = xs[kk];
            const float4* wr = (const float4*)&Wl[((k4 << 2) + kk) << 6];
#pragma unroll
            for (int j4 = 0; j4 < 16; ++j4) {
                float4 wv = wr[j4];   // wave-uniform address -> LDS broadcast
                acc4[j4].x = fmaf(xk, wv.x, acc4[j4].x);
                acc4[j4].y = fmaf(xk, wv.y, acc4[j4].y);
                acc4[j4].z = fmaf(xk, wv.z, acc4[j4].z);
                acc4[j4].w = fmaf(xk, wv.w, acc4[j4].w);
            }
        }
        xq = xn;
    }

    if (MODE == 0) {
        float s = dis[row];
        uint4* go = (uint4*)out;
#pragma unroll
        for (int p = 0; p < 8; ++p) {
            float4 a = acc4[2 * p];
            float4 b = acc4[2 * p + 1];
            uint4 o;
            o.x = (f32_to_bf16_bits(a.y * s) << 16) | f32_to_bf16_bits(a.x * s);
            o.y = (f32_to_bf16_bits(a.w * s) << 16) | f32_to_bf16_bits(a.z * s);
            o.z = (f32_to_bf16_bits(b.y * s) << 16) | f32_to_bf16_bits(b.x * s);
            o.w = (f32_to_bf16_bits(b.w * s) << 16) | f32_to_bf16_bits(b.z * s);
            go[(size_t)row * 8 + p] = o;
        }
    } else {
        const float4* b4 = (const float4*)bias;
        float4* fo = (float4*)out;
#pragma unroll
        for (int p = 0; p < 16; ++p) {
            float4 bb = b4[p];
            float4 a = acc4[p];
            a.x += bb.x; a.y += bb.y; a.z += bb.z; a.w += bb.w;
            fo[(size_t)row * 16 + p] = a;
        }
    }
}

// ---------------------------------------------------------------- pull aggregation
// One wave per dst node. 8 groups x 8 lanes: group g handles edges beg+g, beg+g+8, ...
// lane chunk (lane&7) covers features chk*8..chk*8+7 via one dwordx4 bf16 load.
// out[i] = relu( dis[i] * (g[i] + sum_{e in in(i)} g[col[e]]) + bias )
__global__ __launch_bounds__(256) void agg_kernel(const uint4* __restrict__ g,
                                                  const int* __restrict__ rowptr,
                                                  const int* __restrict__ col,
                                                  const float* __restrict__ dis,
                                                  const float* __restrict__ bias,
                                                  float* __restrict__ out, int n) {
    int wid = (blockIdx.x * 256 + threadIdx.x) >> 6;
    if (wid >= n) return;
    int lane = threadIdx.x & 63;
    int grp = lane >> 3;
    int chk = lane & 7;

    float acc[8];
#pragma unroll
    for (int j = 0; j < 8; ++j) acc[j] = 0.f;

    if (grp == 0) {  // self-loop term
        uint4 q = g[(size_t)wid * 8 + chk];
        add_bf16x8(acc, q);
    }

    int beg = rowptr[wid];
    int end = rowptr[wid + 1];
    for (int e = beg + grp; e < end; e += 8) {
        int s = col[e];                       // same addr across the 8-lane group
        uint4 q = g[(size_t)s * 8 + chk];     // 128B contiguous per group
        add_bf16x8(acc, q);
    }

    // reduce across the 8 groups (lanes with equal chk, stride 8)
#pragma unroll
    for (int m = 8; m < 64; m <<= 1) {
#pragma unroll
        for (int j = 0; j < 8; ++j) acc[j] += __shfl_xor(acc[j], m, 64);
    }

    if (grp == 0) {
        float dv = dis[wid];
        float4 o0, o1;
        const float* bb = bias + chk * 8;
        o0.x = fmaxf(fmaf(acc[0], dv, bb[0]), 0.f);
        o0.y = fmaxf(fmaf(acc[1], dv, bb[1]), 0.f);
        o0.z = fmaxf(fmaf(acc[2], dv, bb[2]), 0.f);
        o0.w = fmaxf(fmaf(acc[3], dv, bb[3]), 0.f);
        o1.x = fmaxf(fmaf(acc[4], dv, bb[4]), 0.f);
        o1.y = fmaxf(fmaf(acc[5], dv, bb[5]), 0.f);
        o1.z = fmaxf(fmaf(acc[6], dv, bb[6]), 0.f);
        o1.w = fmaxf(fmaf(acc[7], dv, bb[7]), 0.f);
        float4* fo = (float4*)out;
        fo[(size_t)wid * 16 + chk * 2 + 0] = o0;
        fo[(size_t)wid * 16 + chk * 2 + 1] = o1;
    }
}

// ---------------------------------------------------------------- launch
extern "C" void kernel_launch(void* const* d_in, const int* in_sizes, int n_in,
                              void* d_out, int out_size, void* d_ws, size_t ws_size,
                              hipStream_t stream) {
    const float* x  = (const float*)d_in[0];
    const int*   ei = (const int*)d_in[1];   // [2,E] int32 (harness converts integer dtypes)
    const float* W1 = (const float*)d_in[2];
    const float* b1 = (const float*)d_in[3];
    const float* W2 = (const float*)d_in[4];
    const float* b2 = (const float*)d_in[5];
    // Wq/bq/Wk/bk (d_in[6..9]) are dead: softmax over a length-1 axis is identity.
    const float* Wv = (const float*)d_in[10];
    const float* bv = (const float*)d_in[11];

    const int N = in_sizes[0] / 64;
    const int E = in_sizes[1] / 2;

    auto align_up = [](size_t v) { return (v + 255) & ~(size_t)255; };
    char* p = (char*)d_ws;
    int*   deg    = (int*)p;    p += align_up((size_t)N * 4);
    int*   cursor = (int*)p;    p += align_up((size_t)N * 4);
    int*   rowptr = (int*)p;    p += align_up((size_t)(N + 1) * 4);
    float* dis    = (float*)p;  p += align_up((size_t)N * 4);
    int*   bsum   = (int*)p;    p += align_up((size_t)2048 * 4);
    int*   col    = (int*)p;    p += align_up((size_t)E * 4);
    uint4* gbuf   = (uint4*)p;  p += align_up((size_t)N * 128);  // bf16 rows
    float* xbuf   = (float*)p;  p += align_up((size_t)N * 256);  // fp32 hidden

    hipMemsetAsync(deg, 0, (size_t)N * 4, stream);
    hipMemsetAsync(cursor, 0, (size_t)N * 4, stream);

    int ebl4 = ((E >> 2) + 255) / 256 + 1;   // +1 covers the tail-edge threads
    int ebl = (E + 255) / 256;
    int nbl = (N + 255) / 256;               // also the scan block count (<=1024 req'd for scan2)
    int abl = (N + 3) / 4;                   // one wave per node, 4 waves per block

    deg_kernel<<<ebl4, 256, 0, stream>>>(ei, deg, E);
    scan1_kernel<<<nbl, 256, 0, stream>>>(deg, bsum, N);
    scan2_kernel<<<1, 1024, 0, stream>>>(bsum, nbl);
    scan3_kernel<<<nbl, 256, 0, stream>>>(deg, bsum, rowptr, dis, N);
    fill_kernel<<<ebl, 256, 0, stream>>>(ei, rowptr, cursor, col, E);

    // layer 1: g = bf16(dis * (x@W1)); xbuf = relu(dis*Agg(g) + b1)
    gemm_kernel<0><<<nbl, 256, 0, stream>>>(x, W1, dis, nullptr, gbuf, N);
    agg_kernel<<<abl, 256, 0, stream>>>(gbuf, rowptr, col, dis, b1, xbuf, N);

    // layer 2
    gemm_kernel<0><<<nbl, 256, 0, stream>>>(xbuf, W2, dis, nullptr, gbuf, N);
    agg_kernel<<<abl, 256, 0, stream>>>(gbuf, rowptr, col, dis, b2, xbuf, N);

    // output: v = xbuf@Wv + bv (attention is identity at seq_len 1)
    gemm_kernel<1><<<nbl, 256, 0, stream>>>(xbuf, Wv, nullptr, bv, d_out, N);
}

// Round 3
// 484.387 us; speedup vs baseline: 1.8531x; 1.3601x over previous
//
#include <hip/hip_runtime.h>
#include <hip/hip_bf16.h>
#include <cstdint>
#include <cstddef>

// D = 64 hardcoded (in_feats == hidden == 64).
// CSR build assumes N <= 131072 (bucket = dst>>9 < 256) and src < 2^23. N=100000 here.

#define BN_SHIFT 9              // 512 nodes per bucket
#define BN 512
#define PCHUNK 4096             // edges per part-block
#define PCAP 48                 // LDS bin capacity (overflow -> fallback path)

static __device__ __forceinline__ uint32_t f32_to_bf16_bits(float f) {
    uint32_t u = __builtin_bit_cast(uint32_t, f);
    u += 0x7fffu + ((u >> 16) & 1u);   // RNE (no NaNs in this problem)
    return u >> 16;
}

static __device__ __forceinline__ void add_bf16x8(float* acc, uint4 q) {
    uint32_t w0 = q.x, w1 = q.y, w2 = q.z, w3 = q.w;
    acc[0] += __builtin_bit_cast(float, w0 << 16);
    acc[1] += __builtin_bit_cast(float, w0 & 0xffff0000u);
    acc[2] += __builtin_bit_cast(float, w1 << 16);
    acc[3] += __builtin_bit_cast(float, w1 & 0xffff0000u);
    acc[4] += __builtin_bit_cast(float, w2 << 16);
    acc[5] += __builtin_bit_cast(float, w2 & 0xffff0000u);
    acc[6] += __builtin_bit_cast(float, w3 << 16);
    acc[7] += __builtin_bit_cast(float, w3 & 0xffff0000u);
}

// ---------------------------------------------------------------- bucket histogram
__global__ __launch_bounds__(256) void hist_kernel(const int* __restrict__ ei,
                                                   int* __restrict__ bcnt, int E) {
    __shared__ int lc[256];
    int tid = threadIdx.x;
    lc[tid] = 0;
    __syncthreads();
    int t = blockIdx.x * 256 + tid;
    int E4 = E >> 2;
    if (t < E4) {
        int4 d = ((const int4*)(ei + E))[t];
        atomicAdd(&lc[d.x >> BN_SHIFT], 1);
        atomicAdd(&lc[d.y >> BN_SHIFT], 1);
        atomicAdd(&lc[d.z >> BN_SHIFT], 1);
        atomicAdd(&lc[d.w >> BN_SHIFT], 1);
    }
    if (t < (E & 3)) atomicAdd(&lc[ei[E + (E4 << 2) + t] >> BN_SHIFT], 1);
    __syncthreads();
    if (lc[tid]) atomicAdd(&bcnt[tid], lc[tid]);
}

// ---------------------------------------------------------------- bucket scan (1 block)
__global__ __launch_bounds__(256) void bscan_kernel(const int* __restrict__ bcnt,
                                                    int* __restrict__ bbase,
                                                    int* __restrict__ gcur) {
    __shared__ int s[256];
    int t = threadIdx.x;
    int v = bcnt[t];
    s[t] = v;
    __syncthreads();
    for (int off = 1; off < 256; off <<= 1) {
        int u = (t >= off) ? s[t - off] : 0;
        __syncthreads();
        s[t] += u;
        __syncthreads();
    }
    bbase[t] = s[t] - v;            // exclusive; == E for t >= NB
    if (t == 255) bbase[256] = s[255];
    gcur[t] = 0;
}

// ---------------------------------------------------------------- partition (pass 1)
// Bin PCHUNK edges by bucket in LDS, flush each bin contiguously after one
// global reservation. pack = src | (dstoff << 23).
__global__ __launch_bounds__(256) void part_kernel(const int* __restrict__ ei,
                                                   const int* __restrict__ bbase,
                                                   int* __restrict__ gcur,
                                                   uint32_t* __restrict__ stage, int E) {
    __shared__ int cnt[256];
    __shared__ int base[256];
    __shared__ uint32_t bins[256 * PCAP];   // 48 KB
    int tid = threadIdx.x;
    cnt[tid] = 0;
    __syncthreads();

    int e0 = blockIdx.x * PCHUNK;
#pragma unroll
    for (int k = 0; k < PCHUNK / 256; ++k) {
        int e = e0 + (k << 8) + tid;
        if (e < E) {
            int s = ei[e];
            int d = ei[E + e];
            int b = d >> BN_SHIFT;
            uint32_t pack = (uint32_t)s | ((uint32_t)(d & (BN - 1)) << 23);
            int pos = atomicAdd(&cnt[b], 1);
            if (pos < PCAP) {
                bins[b * PCAP + pos] = pack;
            } else {  // rare overflow: direct reserved write (scattered, negligible)
                int p = atomicAdd(&gcur[b], 1);
                stage[bbase[b] + p] = pack;
            }
        }
    }
    __syncthreads();

    {   // reserve per-bin ranges
        int c = min(cnt[tid], PCAP);
        base[tid] = c ? atomicAdd(&gcur[tid], c) : 0;
    }
    __syncthreads();

    int wave = tid >> 6, lane = tid & 63;
    for (int b = wave; b < 256; b += 4) {
        int c = min(cnt[b], PCAP);
        if (!c) continue;
        int gb = bbase[b] + base[b];
        for (int i = lane; i < c; i += 64) stage[gb + i] = bins[b * PCAP + i];
    }
}

// ---------------------------------------------------------------- build (pass 2)
// One block per bucket: per-node histogram + scan -> rowptr/dis, then scatter col.
// All col writes land in this bucket's ~64KB window from ONE block (one XCD's L2).
__global__ __launch_bounds__(256) void build_kernel(const uint32_t* __restrict__ stage,
                                                    const int* __restrict__ bbase,
                                                    int* __restrict__ rowptr,
                                                    float* __restrict__ dis,
                                                    int* __restrict__ col, int n) {
    __shared__ int cnt[BN];
    __shared__ int off[BN];
    __shared__ int cur[BN];
    __shared__ int ssum[256];
    int tid = threadIdx.x;
    int b = blockIdx.x;
    int node0 = b << BN_SHIFT;
    int ebase = bbase[b];
    int ecnt = bbase[b + 1] - ebase;

    cnt[tid] = 0; cnt[tid + 256] = 0;
    cur[tid] = 0; cur[tid + 256] = 0;
    __syncthreads();

    for (int i = tid; i < ecnt; i += 256)
        atomicAdd(&cnt[stage[ebase + i] >> 23], 1);
    __syncthreads();

    // exclusive scan of cnt[0..511] with 256 threads (2 elems/thread)
    int c0 = cnt[2 * tid], c1 = cnt[2 * tid + 1];
    int s = c0 + c1;
    ssum[tid] = s;
    __syncthreads();
    for (int o = 1; o < 256; o <<= 1) {
        int u = (tid >= o) ? ssum[tid - o] : 0;
        __syncthreads();
        ssum[tid] += u;
        __syncthreads();
    }
    int ex = ssum[tid] - s;
    off[2 * tid] = ex;
    off[2 * tid + 1] = ex + c0;
    __syncthreads();

    for (int j = tid; j < BN; j += 256) {
        int node = node0 + j;
        if (node < n) {
            rowptr[node] = ebase + off[j];
            dis[node] = rsqrtf((float)(cnt[j] + 1));  // +1 self-loop
        }
    }
    if (b == (int)gridDim.x - 1 && tid == 0) rowptr[n] = ebase + ecnt;  // == E

    for (int i = tid; i < ecnt; i += 256) {
        uint32_t pk = stage[ebase + i];
        int dstoff = pk >> 23;
        int src = pk & 0x7fffff;
        int p = atomicAdd(&cur[dstoff], 1);
        col[ebase + off[dstoff] + p] = src;
    }
}

// ---------------------------------------------------------------- GEMM [N,64]@[64,64]
// MODE 0: out = bf16( (x@W) * dis[row] );  MODE 1: out = fp32( (x@W) + bias )
template <int MODE>
__global__ __launch_bounds__(256) void gemm_kernel(const float* __restrict__ x,
                                                   const float* __restrict__ W,
                                                   const float* __restrict__ dis,
                                                   const float* __restrict__ bias,
                                                   void* __restrict__ out, int n) {
    __shared__ float Wl[64 * 64];
    int t = threadIdx.x;
    {
        const float4* W4 = (const float4*)W;
        float4* Wl4 = (float4*)Wl;
#pragma unroll
        for (int i = 0; i < 4; ++i) Wl4[t + i * 256] = W4[t + i * 256];
    }
    __syncthreads();

    int row = blockIdx.x * 256 + t;
    if (row >= n) return;

    const float4* xr = (const float4*)(x + (size_t)row * 64);
    float4 acc4[16];
#pragma unroll
    for (int p = 0; p < 16; ++p) acc4[p] = make_float4(0.f, 0.f, 0.f, 0.f);

    float4 xq = xr[0];
    for (int k4 = 0; k4 < 16; ++k4) {
        float4 xn = xq;
        if (k4 < 15) xn = xr[k4 + 1];
        float xs[4] = {xq.x, xq.y, xq.z, xq.w};
#pragma unroll
        for (int kk = 0; kk < 4; ++kk) {
            float xk = xs[kk];
            const float4* wr = (const float4*)&Wl[((k4 << 2) + kk) << 6];
#pragma unroll
            for (int j4 = 0; j4 < 16; ++j4) {
                float4 wv = wr[j4];
                acc4[j4].x = fmaf(xk, wv.x, acc4[j4].x);
                acc4[j4].y = fmaf(xk, wv.y, acc4[j4].y);
                acc4[j4].z = fmaf(xk, wv.z, acc4[j4].z);
                acc4[j4].w = fmaf(xk, wv.w, acc4[j4].w);
            }
        }
        xq = xn;
    }

    if (MODE == 0) {
        float s = dis[row];
        uint4* go = (uint4*)out;
#pragma unroll
        for (int p = 0; p < 8; ++p) {
            float4 a = acc4[2 * p];
            float4 bq = acc4[2 * p + 1];
            uint4 o;
            o.x = (f32_to_bf16_bits(a.y * s) << 16) | f32_to_bf16_bits(a.x * s);
            o.y = (f32_to_bf16_bits(a.w * s) << 16) | f32_to_bf16_bits(a.z * s);
            o.z = (f32_to_bf16_bits(bq.y * s) << 16) | f32_to_bf16_bits(bq.x * s);
            o.w = (f32_to_bf16_bits(bq.w * s) << 16) | f32_to_bf16_bits(bq.z * s);
            go[(size_t)row * 8 + p] = o;
        }
    } else {
        const float4* b4 = (const float4*)bias;
        float4* fo = (float4*)out;
#pragma unroll
        for (int p = 0; p < 16; ++p) {
            float4 bb = b4[p];
            float4 a = acc4[p];
            a.x += bb.x; a.y += bb.y; a.z += bb.z; a.w += bb.w;
            fo[(size_t)row * 16 + p] = a;
        }
    }
}

// ---------------------------------------------------------------- pull aggregation
__global__ __launch_bounds__(256) void agg_kernel(const uint4* __restrict__ g,
                                                  const int* __restrict__ rowptr,
                                                  const int* __restrict__ col,
                                                  const float* __restrict__ dis,
                                                  const float* __restrict__ bias,
                                                  float* __restrict__ out, int n) {
    int wid = (blockIdx.x * 256 + threadIdx.x) >> 6;
    if (wid >= n) return;
    int lane = threadIdx.x & 63;
    int grp = lane >> 3;
    int chk = lane & 7;

    float acc[8];
#pragma unroll
    for (int j = 0; j < 8; ++j) acc[j] = 0.f;

    if (grp == 0) {  // self-loop term
        uint4 q = g[(size_t)wid * 8 + chk];
        add_bf16x8(acc, q);
    }

    int beg = rowptr[wid];
    int end = rowptr[wid + 1];
    for (int e = beg + grp; e < end; e += 8) {
        int s = col[e];
        uint4 q = g[(size_t)s * 8 + chk];
        add_bf16x8(acc, q);
    }

#pragma unroll
    for (int m = 8; m < 64; m <<= 1) {
#pragma unroll
        for (int j = 0; j < 8; ++j) acc[j] += __shfl_xor(acc[j], m, 64);
    }

    if (grp == 0) {
        float dv = dis[wid];
        float4 o0, o1;
        const float* bb = bias + chk * 8;
        o0.x = fmaxf(fmaf(acc[0], dv, bb[0]), 0.f);
        o0.y = fmaxf(fmaf(acc[1], dv, bb[1]), 0.f);
        o0.z = fmaxf(fmaf(acc[2], dv, bb[2]), 0.f);
        o0.w = fmaxf(fmaf(acc[3], dv, bb[3]), 0.f);
        o1.x = fmaxf(fmaf(acc[4], dv, bb[4]), 0.f);
        o1.y = fmaxf(fmaf(acc[5], dv, bb[5]), 0.f);
        o1.z = fmaxf(fmaf(acc[6], dv, bb[6]), 0.f);
        o1.w = fmaxf(fmaf(acc[7], dv, bb[7]), 0.f);
        float4* fo = (float4*)out;
        fo[(size_t)wid * 16 + chk * 2 + 0] = o0;
        fo[(size_t)wid * 16 + chk * 2 + 1] = o1;
    }
}

// ---------------------------------------------------------------- launch
extern "C" void kernel_launch(void* const* d_in, const int* in_sizes, int n_in,
                              void* d_out, int out_size, void* d_ws, size_t ws_size,
                              hipStream_t stream) {
    const float* x  = (const float*)d_in[0];
    const int*   ei = (const int*)d_in[1];
    const float* W1 = (const float*)d_in[2];
    const float* b1 = (const float*)d_in[3];
    const float* W2 = (const float*)d_in[4];
    const float* b2 = (const float*)d_in[5];
    // Wq/bq/Wk/bk dead: softmax over a length-1 axis is identity.
    const float* Wv = (const float*)d_in[10];
    const float* bv = (const float*)d_in[11];

    const int N = in_sizes[0] / 64;
    const int E = in_sizes[1] / 2;
    const int NB = (N + BN - 1) >> BN_SHIFT;

    auto align_up = [](size_t v) { return (v + 255) & ~(size_t)255; };
    char* p = (char*)d_ws;
    int*   rowptr = (int*)p;    p += align_up((size_t)(N + 1) * 4);
    float* dis    = (float*)p;  p += align_up((size_t)N * 4);
    int*   bcnt   = (int*)p;    p += align_up((size_t)256 * 4);
    int*   bbase  = (int*)p;    p += align_up((size_t)257 * 4);
    int*   gcur   = (int*)p;    p += align_up((size_t)256 * 4);
    int*   col    = (int*)p;    p += align_up((size_t)E * 4);
    size_t gsz    = (size_t)N * 128 > (size_t)E * 4 ? (size_t)N * 128 : (size_t)E * 4;
    uint4* gbuf   = (uint4*)p;  p += align_up(gsz);              // bf16 rows; aliased by stage
    float* xbuf   = (float*)p;  p += align_up((size_t)N * 256);  // fp32 hidden
    uint32_t* stage = (uint32_t*)gbuf;  // dead before first gemm writes gbuf

    hipMemsetAsync(bcnt, 0, 256 * 4, stream);

    int ebl4 = ((E >> 2) + 255) / 256 + 1;
    int nbl  = (N + 255) / 256;
    int pbl  = (E + PCHUNK - 1) / PCHUNK;
    int abl  = (N + 3) / 4;  // one wave per node

    hist_kernel<<<ebl4, 256, 0, stream>>>(ei, bcnt, E);
    bscan_kernel<<<1, 256, 0, stream>>>(bcnt, bbase, gcur);
    part_kernel<<<pbl, 256, 0, stream>>>(ei, bbase, gcur, stage, E);
    build_kernel<<<NB, 256, 0, stream>>>(stage, bbase, rowptr, dis, col, N);

    // layer 1: g = bf16(dis * (x@W1)); xbuf = relu(dis*Agg(g) + b1)
    gemm_kernel<0><<<nbl, 256, 0, stream>>>(x, W1, dis, nullptr, gbuf, N);
    agg_kernel<<<abl, 256, 0, stream>>>(gbuf, rowptr, col, dis, b1, xbuf, N);

    // layer 2
    gemm_kernel<0><<<nbl, 256, 0, stream>>>(xbuf, W2, dis, nullptr, gbuf, N);
    agg_kernel<<<abl, 256, 0, stream>>>(gbuf, rowptr, col, dis, b2, xbuf, N);

    // output: v = xbuf@Wv + bv (attention identity at seq_len 1)
    gemm_kernel<1><<<nbl, 256, 0, stream>>>(xbuf, Wv, nullptr, bv, d_out, N);
}

// Round 4
// 436.319 us; speedup vs baseline: 2.0573x; 1.1102x over previous
//
#include <hip/hip_runtime.h>
#include <hip/hip_bf16.h>
#include <cstdint>
#include <cstddef>

// D = 64 hardcoded (in_feats == hidden == 64).
// CSR build assumes N <= 131072 (src fits 17 bits; bucket = dst>>8 < 512).

#define BN_SHIFT 8              // 256 nodes per bucket
#define BN 256
#define NBK 512                 // max bucket count
#define PCHUNK 4096             // edges per part-block
#define PCAP 16                 // LDS bin capacity (overflow -> fallback)
#define BCAP 10240              // build LDS edge capacity (mean 8192, +22 sigma)

static __device__ __forceinline__ uint32_t f32_to_bf16_bits(float f) {
    uint32_t u = __builtin_bit_cast(uint32_t, f);
    u += 0x7fffu + ((u >> 16) & 1u);   // RNE (no NaNs in this problem)
    return u >> 16;
}

static __device__ __forceinline__ void add_bf16x8(float* acc, uint4 q) {
    uint32_t w0 = q.x, w1 = q.y, w2 = q.z, w3 = q.w;
    acc[0] += __builtin_bit_cast(float, w0 << 16);
    acc[1] += __builtin_bit_cast(float, w0 & 0xffff0000u);
    acc[2] += __builtin_bit_cast(float, w1 << 16);
    acc[3] += __builtin_bit_cast(float, w1 & 0xffff0000u);
    acc[4] += __builtin_bit_cast(float, w2 << 16);
    acc[5] += __builtin_bit_cast(float, w2 & 0xffff0000u);
    acc[6] += __builtin_bit_cast(float, w3 << 16);
    acc[7] += __builtin_bit_cast(float, w3 & 0xffff0000u);
}

// ---------------------------------------------------------------- bucket histogram
__global__ __launch_bounds__(256) void hist_kernel(const int* __restrict__ ei,
                                                   int* __restrict__ bcnt, int E) {
    __shared__ int lc[NBK];
    int tid = threadIdx.x;
    lc[tid] = 0; lc[tid + 256] = 0;
    __syncthreads();
    int t = blockIdx.x * 256 + tid;
    int E4 = E >> 2;
    if (t < E4) {
        int4 d = ((const int4*)(ei + E))[t];
        atomicAdd(&lc[d.x >> BN_SHIFT], 1);
        atomicAdd(&lc[d.y >> BN_SHIFT], 1);
        atomicAdd(&lc[d.z >> BN_SHIFT], 1);
        atomicAdd(&lc[d.w >> BN_SHIFT], 1);
    }
    if (t < (E & 3)) atomicAdd(&lc[ei[E + (E4 << 2) + t] >> BN_SHIFT], 1);
    __syncthreads();
    if (lc[tid]) atomicAdd(&bcnt[tid], lc[tid]);
    if (lc[tid + 256]) atomicAdd(&bcnt[tid + 256], lc[tid + 256]);
}

// ---------------------------------------------------------------- bucket scan (1 block)
__global__ __launch_bounds__(256) void bscan_kernel(const int* __restrict__ bcnt,
                                                    int* __restrict__ bbase,
                                                    int* __restrict__ gcur) {
    __shared__ int s[256];
    int t = threadIdx.x;
    int c0 = bcnt[2 * t], c1 = bcnt[2 * t + 1];
    int v = c0 + c1;
    s[t] = v;
    __syncthreads();
    for (int off = 1; off < 256; off <<= 1) {
        int u = (t >= off) ? s[t - off] : 0;
        __syncthreads();
        s[t] += u;
        __syncthreads();
    }
    int ex = s[t] - v;
    bbase[2 * t] = ex;
    bbase[2 * t + 1] = ex + c0;
    if (t == 255) bbase[NBK] = ex + c0 + c1;   // == E
    gcur[2 * t] = 0; gcur[2 * t + 1] = 0;
}

// ---------------------------------------------------------------- partition
// Bin PCHUNK edges by bucket in LDS, flush each bin contiguously.
// pack = src | (dstoff << 17)   (src < 2^17, dstoff < 256)
__global__ __launch_bounds__(256) void part_kernel(const int* __restrict__ ei,
                                                   const int* __restrict__ bbase,
                                                   int* __restrict__ gcur,
                                                   uint32_t* __restrict__ stage, int E) {
    __shared__ int cnt[NBK];
    __shared__ int base[NBK];
    __shared__ uint32_t bins[NBK * PCAP];   // 32 KB
    int tid = threadIdx.x;
    cnt[tid] = 0; cnt[tid + 256] = 0;
    __syncthreads();

    int e0 = blockIdx.x * PCHUNK;
#pragma unroll
    for (int k = 0; k < PCHUNK / 256; ++k) {
        int e = e0 + (k << 8) + tid;
        if (e < E) {
            int s = ei[e];
            int d = ei[E + e];
            int b = d >> BN_SHIFT;
            uint32_t pack = (uint32_t)s | ((uint32_t)(d & (BN - 1)) << 17);
            int pos = atomicAdd(&cnt[b], 1);
            if (pos < PCAP) {
                bins[b * PCAP + pos] = pack;
            } else {  // rare overflow: direct reserved write
                int p = atomicAdd(&gcur[b], 1);
                stage[bbase[b] + p] = pack;
            }
        }
    }
    __syncthreads();

    {   // reserve per-bin ranges (2 bins/thread)
        int c0 = min(cnt[tid], PCAP);
        base[tid] = c0 ? atomicAdd(&gcur[tid], c0) : 0;
        int c1 = min(cnt[tid + 256], PCAP);
        base[tid + 256] = c1 ? atomicAdd(&gcur[tid + 256], c1) : 0;
    }
    __syncthreads();

    // flush: each wave handles 4 bins at a time (16 lanes per bin)
    int wave = tid >> 6, lane = tid & 63;
    int sub = lane >> 4, idx = lane & 15;
    for (int b0 = wave * 4; b0 < NBK; b0 += 16) {
        int b = b0 + sub;
        int c = min(cnt[b], PCAP);
        if (idx < c) stage[bbase[b] + base[b] + idx] = bins[b * PCAP + idx];
    }
}

// ---------------------------------------------------------------- build
// One block per bucket. Stages bucket edges in LDS, computes per-node counts,
// writes rowptr/dis/col. Self-loop folded in at slot 0 of each row; col holds
// PRE-SCALED byte offsets (src*128) for agg.
__global__ __launch_bounds__(256) void build_kernel(const uint32_t* __restrict__ stage,
                                                    const int* __restrict__ bbase,
                                                    int* __restrict__ rowptr,
                                                    float* __restrict__ dis,
                                                    int* __restrict__ col, int n) {
    __shared__ uint32_t eb[BCAP];            // 40 KB
    __shared__ int cnt[BN];
    __shared__ int off[BN];
    __shared__ int cur[BN];
    __shared__ int ssum[256];
    int tid = threadIdx.x;
    int b = blockIdx.x;
    int node0 = b << BN_SHIFT;
    int ebase = bbase[b];
    int ecnt = bbase[b + 1] - ebase;
    int colbase = ebase + node0;             // prior buckets' edges + self slots

    cnt[tid] = 0;
    cur[tid] = 0;
    __syncthreads();

    bool fits = (ecnt <= BCAP);
    for (int i = tid; i < ecnt; i += 256) {
        uint32_t pk = stage[ebase + i];
        if (fits) eb[i] = pk;
        atomicAdd(&cnt[pk >> 17], 1);
    }
    __syncthreads();

    // inclusive scan of (cnt+1) -> per-node bases incl. self slot
    int c = cnt[tid] + 1;
    ssum[tid] = c;
    __syncthreads();
    for (int o = 1; o < 256; o <<= 1) {
        int u = (tid >= o) ? ssum[tid - o] : 0;
        __syncthreads();
        ssum[tid] += u;
        __syncthreads();
    }
    int ex = ssum[tid] - c;
    off[tid] = ex;
    int node = node0 + tid;
    if (node <= n) rowptr[node] = colbase + ex;
    if (node < n) {
        dis[node] = rsqrtf((float)c);        // c = deg+1 (self)
        col[colbase + ex] = node << 7;       // self edge, byte offset
    }
    __syncthreads();

    if (fits) {
        for (int i = tid; i < ecnt; i += 256) {
            uint32_t pk = eb[i];
            int doff = pk >> 17;
            int p = atomicAdd(&cur[doff], 1);
            col[colbase + off[doff] + 1 + p] = (int)(pk & 0x1ffff) << 7;
        }
    } else {  // fallback: re-read global (correct for any input)
        for (int i = tid; i < ecnt; i += 256) {
            uint32_t pk = stage[ebase + i];
            int doff = pk >> 17;
            int p = atomicAdd(&cur[doff], 1);
            col[colbase + off[doff] + 1 + p] = (int)(pk & 0x1ffff) << 7;
        }
    }
}

// ---------------------------------------------------------------- GEMM [N,64]@[64,64]
// MODE 0: out = bf16( (x@W) * dis[row] );  MODE 1: out = fp32( (x@W) + bias )
template <int MODE>
__global__ __launch_bounds__(256) void gemm_kernel(const float* __restrict__ x,
                                                   const float* __restrict__ W,
                                                   const float* __restrict__ dis,
                                                   const float* __restrict__ bias,
                                                   void* __restrict__ out, int n) {
    __shared__ float Wl[64 * 64];
    int t = threadIdx.x;
    {
        const float4* W4 = (const float4*)W;
        float4* Wl4 = (float4*)Wl;
#pragma unroll
        for (int i = 0; i < 4; ++i) Wl4[t + i * 256] = W4[t + i * 256];
    }
    __syncthreads();

    int row = blockIdx.x * 256 + t;
    if (row >= n) return;

    const float4* xr = (const float4*)(x + (size_t)row * 64);
    float4 acc4[16];
#pragma unroll
    for (int p = 0; p < 16; ++p) acc4[p] = make_float4(0.f, 0.f, 0.f, 0.f);

    float4 xq = xr[0];
    for (int k4 = 0; k4 < 16; ++k4) {
        float4 xn = xq;
        if (k4 < 15) xn = xr[k4 + 1];
        float xs[4] = {xq.x, xq.y, xq.z, xq.w};
#pragma unroll
        for (int kk = 0; kk < 4; ++kk) {
            float xk = xs[kk];
            const float4* wr = (const float4*)&Wl[((k4 << 2) + kk) << 6];
#pragma unroll
            for (int j4 = 0; j4 < 16; ++j4) {
                float4 wv = wr[j4];
                acc4[j4].x = fmaf(xk, wv.x, acc4[j4].x);
                acc4[j4].y = fmaf(xk, wv.y, acc4[j4].y);
                acc4[j4].z = fmaf(xk, wv.z, acc4[j4].z);
                acc4[j4].w = fmaf(xk, wv.w, acc4[j4].w);
            }
        }
        xq = xn;
    }

    if (MODE == 0) {
        float s = dis[row];
        uint4* go = (uint4*)out;
#pragma unroll
        for (int p = 0; p < 8; ++p) {
            float4 a = acc4[2 * p];
            float4 bq = acc4[2 * p + 1];
            uint4 o;
            o.x = (f32_to_bf16_bits(a.y * s) << 16) | f32_to_bf16_bits(a.x * s);
            o.y = (f32_to_bf16_bits(a.w * s) << 16) | f32_to_bf16_bits(a.z * s);
            o.z = (f32_to_bf16_bits(bq.y * s) << 16) | f32_to_bf16_bits(bq.x * s);
            o.w = (f32_to_bf16_bits(bq.w * s) << 16) | f32_to_bf16_bits(bq.z * s);
            go[(size_t)row * 8 + p] = o;
        }
    } else {
        const float4* b4 = (const float4*)bias;
        float4* fo = (float4*)out;
#pragma unroll
        for (int p = 0; p < 16; ++p) {
            float4 bb = b4[p];
            float4 a = acc4[p];
            a.x += bb.x; a.y += bb.y; a.z += bb.z; a.w += bb.w;
            fo[(size_t)row * 16 + p] = a;
        }
    }
}

// ---------------------------------------------------------------- pull aggregation
// One wave per node; 8 groups x 8 lanes; col holds byte offsets (src*128),
// self-loop included at slot 0. Unrolled x2 for MLP.
__global__ __launch_bounds__(256) void agg_kernel(const char* __restrict__ g,
                                                  const int* __restrict__ rowptr,
                                                  const int* __restrict__ col,
                                                  const float* __restrict__ dis,
                                                  const float* __restrict__ bias,
                                                  float* __restrict__ out, int n) {
    int wid = (blockIdx.x * 256 + threadIdx.x) >> 6;
    if (wid >= n) return;
    int lane = threadIdx.x & 63;
    int grp = lane >> 3;
    int chk16 = (lane & 7) << 4;

    float acc[8];
#pragma unroll
    for (int j = 0; j < 8; ++j) acc[j] = 0.f;

    int beg = rowptr[wid];
    int end = rowptr[wid + 1];
    int e = beg + grp;
    for (; e + 8 < end; e += 16) {
        int o0 = col[e] + chk16;
        int o1 = col[e + 8] + chk16;
        uint4 q0 = *(const uint4*)(g + o0);
        uint4 q1 = *(const uint4*)(g + o1);
        add_bf16x8(acc, q0);
        add_bf16x8(acc, q1);
    }
    if (e < end) {
        int o = col[e] + chk16;
        add_bf16x8(acc, *(const uint4*)(g + o));
    }

#pragma unroll
    for (int m = 8; m < 64; m <<= 1) {
#pragma unroll
        for (int j = 0; j < 8; ++j) acc[j] += __shfl_xor(acc[j], m, 64);
    }

    // all-lane epilogue: lane (chk,grp) writes feature chk*8+grp
    float dv = dis[wid];
    float v = acc[0];
#pragma unroll
    for (int j = 1; j < 8; ++j) v = (grp == j) ? acc[j] : v;
    int f = (chk16 >> 1) + grp;   // chk*8 + grp
    v = fmaxf(fmaf(v, dv, bias[f]), 0.f);
    out[(size_t)wid * 64 + f] = v;
}

// ---------------------------------------------------------------- launch
extern "C" void kernel_launch(void* const* d_in, const int* in_sizes, int n_in,
                              void* d_out, int out_size, void* d_ws, size_t ws_size,
                              hipStream_t stream) {
    const float* x  = (const float*)d_in[0];
    const int*   ei = (const int*)d_in[1];
    const float* W1 = (const float*)d_in[2];
    const float* b1 = (const float*)d_in[3];
    const float* W2 = (const float*)d_in[4];
    const float* b2 = (const float*)d_in[5];
    // Wq/bq/Wk/bk dead: softmax over a length-1 axis is identity.
    const float* Wv = (const float*)d_in[10];
    const float* bv = (const float*)d_in[11];

    const int N = in_sizes[0] / 64;
    const int E = in_sizes[1] / 2;
    const int NB = (N + BN - 1) >> BN_SHIFT;

    auto align_up = [](size_t v) { return (v + 255) & ~(size_t)255; };
    char* p = (char*)d_ws;
    int*   rowptr = (int*)p;    p += align_up((size_t)(N + 1) * 4);
    float* dis    = (float*)p;  p += align_up((size_t)N * 4);
    int*   bcnt   = (int*)p;    p += align_up((size_t)NBK * 4);
    int*   bbase  = (int*)p;    p += align_up((size_t)(NBK + 1) * 4);
    int*   gcur   = (int*)p;    p += align_up((size_t)NBK * 4);
    int*   col    = (int*)p;    p += align_up((size_t)(E + N + BN) * 4);
    size_t gsz    = (size_t)N * 128 > (size_t)E * 4 ? (size_t)N * 128 : (size_t)E * 4;
    char*  gbuf   = p;          p += align_up(gsz);              // bf16 rows; stage alias
    float* xbuf   = (float*)p;  p += align_up((size_t)N * 256);  // fp32 hidden
    uint32_t* stage = (uint32_t*)gbuf;   // dead before first gemm writes gbuf

    hipMemsetAsync(bcnt, 0, NBK * 4, stream);

    int ebl4 = ((E >> 2) + 255) / 256 + 1;
    int nbl  = (N + 255) / 256;
    int pbl  = (E + PCHUNK - 1) / PCHUNK;
    int abl  = (N + 3) / 4;  // one wave per node

    hist_kernel<<<ebl4, 256, 0, stream>>>(ei, bcnt, E);
    bscan_kernel<<<1, 256, 0, stream>>>(bcnt, bbase, gcur);
    part_kernel<<<pbl, 256, 0, stream>>>(ei, bbase, gcur, stage, E);
    build_kernel<<<NB, 256, 0, stream>>>(stage, bbase, rowptr, dis, col, N);

    // layer 1: g = bf16(dis * (x@W1)); xbuf = relu(dis*Agg(g) + b1)
    gemm_kernel<0><<<nbl, 256, 0, stream>>>(x, W1, dis, nullptr, gbuf, N);
    agg_kernel<<<abl, 256, 0, stream>>>(gbuf, rowptr, col, dis, b1, xbuf, N);

    // layer 2
    gemm_kernel<0><<<nbl, 256, 0, stream>>>(xbuf, W2, dis, nullptr, gbuf, N);
    agg_kernel<<<abl, 256, 0, stream>>>(gbuf, rowptr, col, dis, b2, xbuf, N);

    // output: v = xbuf@Wv + bv (attention identity at seq_len 1)
    gemm_kernel<1><<<nbl, 256, 0, stream>>>(xbuf, Wv, nullptr, bv, d_out, N);
}

// Round 5
// 350.755 us; speedup vs baseline: 2.5591x; 1.2439x over previous
//
#include <hip/hip_runtime.h>
#include <hip/hip_bf16.h>
#include <cstdint>
#include <cstddef>

// D = 64 hardcoded (in_feats == hidden == 64).
// CSR build assumes N <= 131072 (src fits 17 bits; bucket = dst>>8 < 512)
// and E <= 2048*4096 (pscan vals[] capacity).

#define BN_SHIFT 8              // 256 nodes per bucket
#define BN 256
#define NBK 512                 // max bucket count
#define PCHUNK 4096             // edges per hist/part block
#define PCAP 16                 // LDS bin capacity (overflow -> direct exact-slot write)
#define BCAP 10240              // build LDS edge capacity (mean 8192)

static __device__ __forceinline__ uint32_t f32_to_bf16_bits(float f) {
    uint32_t u = __builtin_bit_cast(uint32_t, f);
    u += 0x7fffu + ((u >> 16) & 1u);   // RNE (no NaNs in this problem)
    return u >> 16;
}

static __device__ __forceinline__ void add_bf16x8(float* acc, uint4 q) {
    uint32_t w0 = q.x, w1 = q.y, w2 = q.z, w3 = q.w;
    acc[0] += __builtin_bit_cast(float, w0 << 16);
    acc[1] += __builtin_bit_cast(float, w0 & 0xffff0000u);
    acc[2] += __builtin_bit_cast(float, w1 << 16);
    acc[3] += __builtin_bit_cast(float, w1 & 0xffff0000u);
    acc[4] += __builtin_bit_cast(float, w2 << 16);
    acc[5] += __builtin_bit_cast(float, w2 & 0xffff0000u);
    acc[6] += __builtin_bit_cast(float, w3 << 16);
    acc[7] += __builtin_bit_cast(float, w3 & 0xffff0000u);
}

// ---------------------------------------------------------------- hist
// Per-block LDS histogram of PCHUNK dsts; dense row write to pcnt. NO global atomics.
__global__ __launch_bounds__(256) void hist_kernel(const int* __restrict__ ei,
                                                   int* __restrict__ pcnt, int E) {
    __shared__ int lc[NBK];
    int tid = threadIdx.x;
    lc[tid] = 0; lc[tid + 256] = 0;
    __syncthreads();

    int e0 = blockIdx.x * PCHUNK;
    int m = min(PCHUNK, E - e0);
    const int* dsts = ei + E + e0;
    if ((((uintptr_t)dsts) & 15) == 0) {
        int m4 = m >> 2;
        for (int t = tid; t < m4; t += 256) {
            int4 d = ((const int4*)dsts)[t];
            atomicAdd(&lc[d.x >> BN_SHIFT], 1);
            atomicAdd(&lc[d.y >> BN_SHIFT], 1);
            atomicAdd(&lc[d.z >> BN_SHIFT], 1);
            atomicAdd(&lc[d.w >> BN_SHIFT], 1);
        }
        for (int i = (m4 << 2) + tid; i < m; i += 256)
            atomicAdd(&lc[dsts[i] >> BN_SHIFT], 1);
    } else {
        for (int i = tid; i < m; i += 256)
            atomicAdd(&lc[dsts[i] >> BN_SHIFT], 1);
    }
    __syncthreads();
    int* row = pcnt + (size_t)blockIdx.x * NBK;
    row[tid] = lc[tid];
    row[tid + 256] = lc[tid + 256];
}

// ---------------------------------------------------------------- pscan
// One block per bucket: exclusive scan of its pcnt column (in place), total -> bcnt.
__global__ __launch_bounds__(256) void pscan_kernel(int* __restrict__ pcnt,
                                                    int* __restrict__ bcnt, int PB) {
    __shared__ int ss[256];
    int b = blockIdx.x;
    int tid = threadIdx.x;
    int iper = (PB + 255) >> 8;          // <= 8 by the E-capacity assumption
    int i0 = tid * iper;
    int i1 = min(PB, i0 + iper);
    int vals[8];
    int s = 0;
    for (int i = i0, k = 0; i < i1; ++i, ++k) {
        vals[k] = pcnt[(size_t)i * NBK + b];
        s += vals[k];
    }
    ss[tid] = s;
    __syncthreads();
    for (int o = 1; o < 256; o <<= 1) {
        int u = (tid >= o) ? ss[tid - o] : 0;
        __syncthreads();
        ss[tid] += u;
        __syncthreads();
    }
    int run = ss[tid] - s;
    for (int i = i0, k = 0; i < i1; ++i, ++k) {
        pcnt[(size_t)i * NBK + b] = run;
        run += vals[k];
    }
    if (tid == 255) bcnt[b] = ss[255];
}

// ---------------------------------------------------------------- bscan (1 block)
__global__ __launch_bounds__(256) void bscan_kernel(const int* __restrict__ bcnt,
                                                    int* __restrict__ bbase) {
    __shared__ int s[256];
    int t = threadIdx.x;
    int c0 = bcnt[2 * t], c1 = bcnt[2 * t + 1];
    int v = c0 + c1;
    s[t] = v;
    __syncthreads();
    for (int off = 1; off < 256; off <<= 1) {
        int u = (t >= off) ? s[t - off] : 0;
        __syncthreads();
        s[t] += u;
        __syncthreads();
    }
    int ex = s[t] - v;
    bbase[2 * t] = ex;
    bbase[2 * t + 1] = ex + c0;
    if (t == 255) bbase[NBK] = ex + c0 + c1;   // == E
}

// ---------------------------------------------------------------- partition
// Deterministic: this block's exact base per bucket = bbase[b] + poff[blk][b].
// pack = src | (dstoff << 17). LDS bins + exact-slot overflow. NO global atomics.
__global__ __launch_bounds__(256) void part_kernel(const int* __restrict__ ei,
                                                   const int* __restrict__ bbase,
                                                   const int* __restrict__ poff,
                                                   uint32_t* __restrict__ stage, int E) {
    __shared__ int cnt[NBK];
    __shared__ int base[NBK];
    __shared__ uint32_t bins[NBK * PCAP];   // 32 KB
    int tid = threadIdx.x;
    cnt[tid] = 0; cnt[tid + 256] = 0;
    {
        const int* prow = poff + (size_t)blockIdx.x * NBK;
        base[tid] = bbase[tid] + prow[tid];
        base[tid + 256] = bbase[tid + 256] + prow[tid + 256];
    }
    __syncthreads();

    int e0 = blockIdx.x * PCHUNK;
#pragma unroll
    for (int k = 0; k < PCHUNK / 256; ++k) {
        int e = e0 + (k << 8) + tid;
        if (e < E) {
            int s = ei[e];
            int d = ei[E + e];
            int b = d >> BN_SHIFT;
            uint32_t pack = (uint32_t)s | ((uint32_t)(d & (BN - 1)) << 17);
            int pos = atomicAdd(&cnt[b], 1);
            if (pos < PCAP) bins[b * PCAP + pos] = pack;
            else stage[base[b] + pos] = pack;     // exact slot, race-free
        }
    }
    __syncthreads();

    // flush: each wave handles 4 bins at a time (16 lanes per bin)
    int wave = tid >> 6, lane = tid & 63;
    int sub = lane >> 4, idx = lane & 15;
    for (int b0 = wave * 4; b0 < NBK; b0 += 16) {
        int b = b0 + sub;
        int c = min(cnt[b], PCAP);
        if (idx < c) stage[base[b] + idx] = bins[b * PCAP + idx];
    }
}

// ---------------------------------------------------------------- build
// One block per bucket. Self-loop folded at slot 0; col holds byte offsets (src*128).
__global__ __launch_bounds__(256) void build_kernel(const uint32_t* __restrict__ stage,
                                                    const int* __restrict__ bbase,
                                                    int* __restrict__ rowptr,
                                                    float* __restrict__ dis,
                                                    int* __restrict__ col, int n) {
    __shared__ uint32_t eb[BCAP];            // 40 KB
    __shared__ int cnt[BN];
    __shared__ int off[BN];
    __shared__ int cur[BN];
    __shared__ int ssum[256];
    int tid = threadIdx.x;
    int b = blockIdx.x;
    int node0 = b << BN_SHIFT;
    int ebase = bbase[b];
    int ecnt = bbase[b + 1] - ebase;
    int colbase = ebase + node0;             // prior buckets' edges + self slots

    cnt[tid] = 0;
    cur[tid] = 0;
    __syncthreads();

    bool fits = (ecnt <= BCAP);
    for (int i = tid; i < ecnt; i += 256) {
        uint32_t pk = stage[ebase + i];
        if (fits) eb[i] = pk;
        atomicAdd(&cnt[pk >> 17], 1);
    }
    __syncthreads();

    int c = cnt[tid] + 1;                    // + self slot
    ssum[tid] = c;
    __syncthreads();
    for (int o = 1; o < 256; o <<= 1) {
        int u = (tid >= o) ? ssum[tid - o] : 0;
        __syncthreads();
        ssum[tid] += u;
        __syncthreads();
    }
    int ex = ssum[tid] - c;
    off[tid] = ex;
    int node = node0 + tid;
    if (node <= n) rowptr[node] = colbase + ex;
    if (node < n) {
        dis[node] = rsqrtf((float)c);        // c = deg+1 (self)
        col[colbase + ex] = node << 7;       // self edge, byte offset
    }
    __syncthreads();

    if (fits) {
        for (int i = tid; i < ecnt; i += 256) {
            uint32_t pk = eb[i];
            int doff = pk >> 17;
            int p = atomicAdd(&cur[doff], 1);
            col[colbase + off[doff] + 1 + p] = (int)(pk & 0x1ffff) << 7;
        }
    } else {
        for (int i = tid; i < ecnt; i += 256) {
            uint32_t pk = stage[ebase + i];
            int doff = pk >> 17;
            int p = atomicAdd(&cur[doff], 1);
            col[colbase + off[doff] + 1 + p] = (int)(pk & 0x1ffff) << 7;
        }
    }
}

// ---------------------------------------------------------------- GEMM [N,64]@[64,64]
// MODE 0: out = bf16( (x@W) * dis[row] );  MODE 1: out = fp32( (x@W) + bias )
template <int MODE>
__global__ __launch_bounds__(256) void gemm_kernel(const float* __restrict__ x,
                                                   const float* __restrict__ W,
                                                   const float* __restrict__ dis,
                                                   const float* __restrict__ bias,
                                                   void* __restrict__ out, int n) {
    __shared__ float Wl[64 * 64];
    int t = threadIdx.x;
    {
        const float4* W4 = (const float4*)W;
        float4* Wl4 = (float4*)Wl;
#pragma unroll
        for (int i = 0; i < 4; ++i) Wl4[t + i * 256] = W4[t + i * 256];
    }
    __syncthreads();

    int row = blockIdx.x * 256 + t;
    if (row >= n) return;

    const float4* xr = (const float4*)(x + (size_t)row * 64);
    float4 acc4[16];
#pragma unroll
    for (int p = 0; p < 16; ++p) acc4[p] = make_float4(0.f, 0.f, 0.f, 0.f);

    float4 xq = xr[0];
    for (int k4 = 0; k4 < 16; ++k4) {
        float4 xn = xq;
        if (k4 < 15) xn = xr[k4 + 1];
        float xs[4] = {xq.x, xq.y, xq.z, xq.w};
#pragma unroll
        for (int kk = 0; kk < 4; ++kk) {
            float xk = xs[kk];
            const float4* wr = (const float4*)&Wl[((k4 << 2) + kk) << 6];
#pragma unroll
            for (int j4 = 0; j4 < 16; ++j4) {
                float4 wv = wr[j4];
                acc4[j4].x = fmaf(xk, wv.x, acc4[j4].x);
                acc4[j4].y = fmaf(xk, wv.y, acc4[j4].y);
                acc4[j4].z = fmaf(xk, wv.z, acc4[j4].z);
                acc4[j4].w = fmaf(xk, wv.w, acc4[j4].w);
            }
        }
        xq = xn;
    }

    if (MODE == 0) {
        float s = dis[row];
        uint4* go = (uint4*)out;
#pragma unroll
        for (int p = 0; p < 8; ++p) {
            float4 a = acc4[2 * p];
            float4 bq = acc4[2 * p + 1];
            uint4 o;
            o.x = (f32_to_bf16_bits(a.y * s) << 16) | f32_to_bf16_bits(a.x * s);
            o.y = (f32_to_bf16_bits(a.w * s) << 16) | f32_to_bf16_bits(a.z * s);
            o.z = (f32_to_bf16_bits(bq.y * s) << 16) | f32_to_bf16_bits(bq.x * s);
            o.w = (f32_to_bf16_bits(bq.w * s) << 16) | f32_to_bf16_bits(bq.z * s);
            go[(size_t)row * 8 + p] = o;
        }
    } else {
        const float4* b4 = (const float4*)bias;
        float4* fo = (float4*)out;
#pragma unroll
        for (int p = 0; p < 16; ++p) {
            float4 bb = b4[p];
            float4 a = acc4[p];
            a.x += bb.x; a.y += bb.y; a.z += bb.z; a.w += bb.w;
            fo[(size_t)row * 16 + p] = a;
        }
    }
}

// ---------------------------------------------------------------- pull aggregation
// One wave per node; 8 groups x 8 lanes; col holds byte offsets (src*128),
// self-loop at slot 0. Unrolled x2 for MLP.
__global__ __launch_bounds__(256) void agg_kernel(const char* __restrict__ g,
                                                  const int* __restrict__ rowptr,
                                                  const int* __restrict__ col,
                                                  const float* __restrict__ dis,
                                                  const float* __restrict__ bias,
                                                  float* __restrict__ out, int n) {
    int wid = (blockIdx.x * 256 + threadIdx.x) >> 6;
    if (wid >= n) return;
    int lane = threadIdx.x & 63;
    int grp = lane >> 3;
    int chk16 = (lane & 7) << 4;

    float acc[8];
#pragma unroll
    for (int j = 0; j < 8; ++j) acc[j] = 0.f;

    int beg = rowptr[wid];
    int end = rowptr[wid + 1];
    int e = beg + grp;
    for (; e + 8 < end; e += 16) {
        int o0 = col[e] + chk16;
        int o1 = col[e + 8] + chk16;
        uint4 q0 = *(const uint4*)(g + o0);
        uint4 q1 = *(const uint4*)(g + o1);
        add_bf16x8(acc, q0);
        add_bf16x8(acc, q1);
    }
    if (e < end) {
        int o = col[e] + chk16;
        add_bf16x8(acc, *(const uint4*)(g + o));
    }

#pragma unroll
    for (int m = 8; m < 64; m <<= 1) {
#pragma unroll
        for (int j = 0; j < 8; ++j) acc[j] += __shfl_xor(acc[j], m, 64);
    }

    // all-lane epilogue: lane (chk,grp) writes feature chk*8+grp
    float dv = dis[wid];
    float v = acc[0];
#pragma unroll
    for (int j = 1; j < 8; ++j) v = (grp == j) ? acc[j] : v;
    int f = (chk16 >> 1) + grp;   // chk*8 + grp
    v = fmaxf(fmaf(v, dv, bias[f]), 0.f);
    out[(size_t)wid * 64 + f] = v;
}

// ---------------------------------------------------------------- launch
extern "C" void kernel_launch(void* const* d_in, const int* in_sizes, int n_in,
                              void* d_out, int out_size, void* d_ws, size_t ws_size,
                              hipStream_t stream) {
    const float* x  = (const float*)d_in[0];
    const int*   ei = (const int*)d_in[1];
    const float* W1 = (const float*)d_in[2];
    const float* b1 = (const float*)d_in[3];
    const float* W2 = (const float*)d_in[4];
    const float* b2 = (const float*)d_in[5];
    // Wq/bq/Wk/bk dead: softmax over a length-1 axis is identity.
    const float* Wv = (const float*)d_in[10];
    const float* bv = (const float*)d_in[11];

    const int N = in_sizes[0] / 64;
    const int E = in_sizes[1] / 2;
    const int NB = (N + BN - 1) >> BN_SHIFT;
    const int PB = (E + PCHUNK - 1) / PCHUNK;

    auto align_up = [](size_t v) { return (v + 255) & ~(size_t)255; };
    char* p = (char*)d_ws;
    int*   rowptr = (int*)p;    p += align_up((size_t)(N + 1) * 4);
    float* dis    = (float*)p;  p += align_up((size_t)N * 4);
    int*   pcnt   = (int*)p;    p += align_up((size_t)PB * NBK * 4);
    int*   bcnt   = (int*)p;    p += align_up((size_t)NBK * 4);
    int*   bbase  = (int*)p;    p += align_up((size_t)(NBK + 1) * 4);
    int*   col    = (int*)p;    p += align_up((size_t)(E + N + BN) * 4);
    size_t gsz    = (size_t)N * 128 > (size_t)E * 4 ? (size_t)N * 128 : (size_t)E * 4;
    char*  gbuf   = p;          p += align_up(gsz);              // bf16 rows; stage alias
    float* xbuf   = (float*)p;  p += align_up((size_t)N * 256);  // fp32 hidden
    uint32_t* stage = (uint32_t*)gbuf;   // dead before first gemm writes gbuf

    int nbl = (N + 255) / 256;
    int abl = (N + 3) / 4;  // one wave per node

    hist_kernel<<<PB, 256, 0, stream>>>(ei, pcnt, E);
    pscan_kernel<<<NBK, 256, 0, stream>>>(pcnt, bcnt, PB);
    bscan_kernel<<<1, 256, 0, stream>>>(bcnt, bbase);
    part_kernel<<<PB, 256, 0, stream>>>(ei, bbase, pcnt, stage, E);
    build_kernel<<<NB, 256, 0, stream>>>(stage, bbase, rowptr, dis, col, N);

    // layer 1: g = bf16(dis * (x@W1)); xbuf = relu(dis*Agg(g) + b1)
    gemm_kernel<0><<<nbl, 256, 0, stream>>>(x, W1, dis, nullptr, gbuf, N);
    agg_kernel<<<abl, 256, 0, stream>>>(gbuf, rowptr, col, dis, b1, xbuf, N);

    // layer 2
    gemm_kernel<0><<<nbl, 256, 0, stream>>>(xbuf, W2, dis, nullptr, gbuf, N);
    agg_kernel<<<abl, 256, 0, stream>>>(gbuf, rowptr, col, dis, b2, xbuf, N);

    // output: v = xbuf@Wv + bv (attention identity at seq_len 1)
    gemm_kernel<1><<<nbl, 256, 0, stream>>>(xbuf, Wv, nullptr, bv, d_out, N);
}